// Round 14
// baseline (398.434 us; speedup 1.0000x reference)
//
#include <hip/hip_runtime.h>
#include <hip/hip_bf16.h>

// QLayerQuantum: out[b][h] = sum_k cumprod(cos(x[b]))[k] * W[h][k] + bias[h]
// B=65536, NQ=32, H=1024.
//
// Measured so far (subtraction method, O+Kz = 217.6us harness floor):
//   r5  fused LDS:        Kg ~ 118us
//   r11 2col/thread reg:  Kg ~ 85us   (vs 46us write floor; fills prove 6.4TB/s)
//   r13 +prefetch:        Kg ~ 85us   (NEUTRAL -> z-latency not the limiter)
// r14 theory: fills hit 6.4TB/s with 8 waves/SIMD; we had 4 (110 VGPR).
// Measured 85 ~= VALU(27) + HBM(43) SUM, i.e. no overlap -> TLP-starved.
// Single change: 1 col/thread (W=32 regs, ~60-80 VGPR total) + 512-thr
// blocks -> ~6-8 waves/SIMD. Stores narrow to dword (256B/wave): if Kg
// INCREASES instead, store width is the real lever (next: 4-col variant).

#define B_TOT 65536
#define NQ    32
#define H_TOT 1024
#define ROWS_PER_BLK 64
#define THREADS 512
#define COLS_PER_BLK 512   // 512 threads * 1 col

__global__ __launch_bounds__(256) void zscan_kernel(
    const float* __restrict__ x,   // [B][NQ]
    float* __restrict__ z)         // [B][NQ] out
{
    const int g = threadIdx.x >> 5;      // 8 row-groups per block
    const int l = threadIdx.x & 31;
    const int row = blockIdx.x * 8 + g;
    float v = __cosf(x[row * NQ + l]);
#pragma unroll
    for (int d = 1; d < 32; d <<= 1) {   // inclusive product scan over 32 lanes
        float o = __shfl_up(v, d, 32);
        if (l >= d) v *= o;
    }
    z[row * NQ + l] = v;
}

__global__ __launch_bounds__(THREADS) void gemm_kernel(
    const float* __restrict__ z,    // [B][NQ]
    const float* __restrict__ W,    // [H][NQ]
    const float* __restrict__ bias, // [H]
    float* __restrict__ out)        // [B][H]
{
    const int tid = threadIdx.x;
    const int r0  = blockIdx.x * ROWS_PER_BLK;
    const int c   = blockIdx.y * COLS_PER_BLK + tid;   // one col per thread

    // ---- W column c into 32 registers (128 B contiguous per thread;
    //      wave covers 8 KB contiguous in 8 float4 instrs) ----
    float w[NQ];
    const float4* wg = reinterpret_cast<const float4*>(W + (size_t)c * NQ);
#pragma unroll
    for (int i = 0; i < 8; ++i) {
        float4 a = wg[i];
        w[4*i+0] = a.x; w[4*i+1] = a.y; w[4*i+2] = a.z; w[4*i+3] = a.w;
    }
    const float bc = bias[c];

    const float4* zp = reinterpret_cast<const float4*>(z + (size_t)r0 * NQ);
    float* op = out + (size_t)r0 * H_TOT + c;

#pragma unroll 1
    for (int r = 0; r < ROWS_PER_BLK; ++r) {
        float zk[NQ];                       // statically indexed -> registers
#pragma unroll
        for (int i = 0; i < 8; ++i) {
            float4 t = zp[r * 8 + i];       // uniform address, L1-hot
            zk[4*i+0] = t.x; zk[4*i+1] = t.y; zk[4*i+2] = t.z; zk[4*i+3] = t.w;
        }
        float a = bc;
#pragma unroll
        for (int k = 0; k < NQ; ++k) a += zk[k] * w[k];
        __builtin_nontemporal_store(a, op + (size_t)r * H_TOT);
    }
}

extern "C" void kernel_launch(void* const* d_in, const int* in_sizes, int n_in,
                              void* d_out, int out_size, void* d_ws, size_t ws_size,
                              hipStream_t stream) {
    const float* x = (const float*)d_in[0];
    const float* W = (const float*)d_in[1];
    const float* b = (const float*)d_in[2];
    float* out = (float*)d_out;
    float* z   = (float*)d_ws;           // 8 MB of the 1 GiB workspace

    zscan_kernel<<<dim3(B_TOT / 8), dim3(256), 0, stream>>>(x, z);
    // Launched TWICE on purpose (idempotent): Kg = dur - 217.6 halved.
    gemm_kernel<<<dim3(B_TOT / ROWS_PER_BLK, H_TOT / COLS_PER_BLK),
                  dim3(THREADS), 0, stream>>>(z, W, b, out);
    gemm_kernel<<<dim3(B_TOT / ROWS_PER_BLK, H_TOT / COLS_PER_BLK),
                  dim3(THREADS), 0, stream>>>(z, W, b, out);
}

// Round 15
// 376.235 us; speedup vs baseline: 1.0590x; 1.0590x over previous
//
#include <hip/hip_runtime.h>
#include <hip/hip_bf16.h>

// QLayerQuantum: out[b][h] = sum_k cumprod(cos(x[b]))[k] * W[h][k] + bias[h]
// B=65536, NQ=32, H=1024.
//
// Kg ledger (subtraction method, harness floor O+Kz = 217.6us):
//   r5  fused LDS:            Kg ~ 118
//   r11 2col/reg, float2 NT:  Kg ~ 85   <- baseline
//   r13 +prefetch:            Kg ~ 85   (z-latency not the stall)
//   r14 1col, 8 waves/SIMD:   Kg ~ 90   (occupancy not the stall)
// All ~2x the 43us write floor; harness fill (REGULAR stores) = 6.4 TB/s.
// Shared-resource saturation signature -> suspect: NONTEMPORAL stores cap
// the write path (~3 TB/s, L2-bypass). r15 single change: r11 kernel with
// regular stores. Predict Kg -> 50-55 (dur ~320) if right; ~387 if wrong.

#define B_TOT 65536
#define NQ    32
#define H_TOT 1024
#define ROWS_PER_BLK 64
#define COLS_PER_BLK 512   // 256 threads * 2 cols

__global__ __launch_bounds__(256) void zscan_kernel(
    const float* __restrict__ x,   // [B][NQ]
    float* __restrict__ z)         // [B][NQ] out
{
    const int g = threadIdx.x >> 5;      // 8 row-groups per block
    const int l = threadIdx.x & 31;
    const int row = blockIdx.x * 8 + g;
    float v = __cosf(x[row * NQ + l]);
#pragma unroll
    for (int d = 1; d < 32; d <<= 1) {   // inclusive product scan over 32 lanes
        float o = __shfl_up(v, d, 32);
        if (l >= d) v *= o;
    }
    z[row * NQ + l] = v;
}

__global__ __launch_bounds__(256) void gemm_kernel(
    const float* __restrict__ z,    // [B][NQ]
    const float* __restrict__ W,    // [H][NQ]
    const float* __restrict__ bias, // [H]
    float* __restrict__ out)        // [B][H]
{
    const int tid = threadIdx.x;
    const int r0  = blockIdx.x * ROWS_PER_BLK;
    const int c0  = blockIdx.y * COLS_PER_BLK + tid * 2;

    // ---- W columns c0, c0+1 into registers (one-time, L2-hot) ----
    float w0[NQ], w1[NQ];
    const float4* wg0 = reinterpret_cast<const float4*>(W + (size_t)c0 * NQ);
    const float4* wg1 = reinterpret_cast<const float4*>(W + (size_t)(c0 + 1) * NQ);
#pragma unroll
    for (int i = 0; i < 8; ++i) {
        float4 a = wg0[i];
        w0[4*i+0] = a.x; w0[4*i+1] = a.y; w0[4*i+2] = a.z; w0[4*i+3] = a.w;
        float4 b = wg1[i];
        w1[4*i+0] = b.x; w1[4*i+1] = b.y; w1[4*i+2] = b.z; w1[4*i+3] = b.w;
    }
    const float b0 = bias[c0];
    const float b1 = bias[c0 + 1];

    const float4* zp = reinterpret_cast<const float4*>(z + (size_t)r0 * NQ);
    float* op = out + (size_t)r0 * H_TOT + c0;

#pragma unroll 1
    for (int r = 0; r < ROWS_PER_BLK; ++r) {
        float zk[NQ];                       // statically indexed -> registers
#pragma unroll
        for (int i = 0; i < 8; ++i) {
            float4 t = zp[r * 8 + i];       // uniform address: s_load / bcast
            zk[4*i+0] = t.x; zk[4*i+1] = t.y; zk[4*i+2] = t.z; zk[4*i+3] = t.w;
        }
        float a0 = b0, a1 = b1;
#pragma unroll
        for (int k = 0; k < NQ; ++k) {
            a0 += zk[k] * w0[k];
            a1 += zk[k] * w1[k];
        }
        // REGULAR store (the single change vs r11): write-back through L2,
        // drain at fill-proven 6.4 TB/s instead of the suspected nt cap.
        float2 o; o.x = a0; o.y = a1;
        *reinterpret_cast<float2*>(op + (size_t)r * H_TOT) = o;
    }
}

extern "C" void kernel_launch(void* const* d_in, const int* in_sizes, int n_in,
                              void* d_out, int out_size, void* d_ws, size_t ws_size,
                              hipStream_t stream) {
    const float* x = (const float*)d_in[0];
    const float* W = (const float*)d_in[1];
    const float* b = (const float*)d_in[2];
    float* out = (float*)d_out;
    float* z   = (float*)d_ws;           // 8 MB of the 1 GiB workspace

    zscan_kernel<<<dim3(B_TOT / 8), dim3(256), 0, stream>>>(x, z);
    // Launched TWICE on purpose (idempotent): Kg = (dur - 217.6)/2.
    gemm_kernel<<<dim3(B_TOT / ROWS_PER_BLK, H_TOT / COLS_PER_BLK),
                  dim3(256), 0, stream>>>(z, W, b, out);
    gemm_kernel<<<dim3(B_TOT / ROWS_PER_BLK, H_TOT / COLS_PER_BLK),
                  dim3(256), 0, stream>>>(z, W, b, out);
}